// Round 16
// baseline (727.837 us; speedup 1.0000x reference)
//
#include <hip/hip_runtime.h>
#include <math.h>

// B=32, R=16384, C=16, IC=16, OC=16, 3 routing iterations.
// x: (B,C,IC) fp32; W: (R,C,OC,IC) fp32 (256 MB); out: (B,C,OC) fp32.
//
// R16: ONE dispatch. 512 blocks (2/CU, all co-resident: 68KB LDS<=80, 512 thr,
// <=128 VGPR) with a guarded device-scope spin barrier between the 3 W-phases.
// Purpose: (a) delete 4 launch gaps + small kernels; (b) k_caps becomes the
// longest dispatch -> rocprof top-5 finally shows the hot loop's counters
// (FETCH/TCC/VALU/VGPR) after 6 blind rounds; (c) per-block W-slice (512 KB)
// re-read across phases while L2/L3-warm (phase 1 walks it in reverse).
// Math: single-term fp16 paired-route mfma_32x32x16 (R15, absmax 3.9e-3 vs
// threshold 1.5e-2); DMA staging with source-permuted chunks (R14); vmcnt(4)
// fixed (R15's vmcnt(8) was a no-op -> DMA/ds_read race).
// R12 lesson: cooperative-launch API fails under graph capture; manual spin
// with plain launch + agent-scope atomics instead (G16: per-XCD L2).

typedef _Float16 half8_t __attribute__((ext_vector_type(8)));
typedef float f32x16_t __attribute__((ext_vector_type(16)));

__device__ __forceinline__ void gload_lds16(const void* g, void* l) {
  __builtin_amdgcn_global_load_lds(
      (const __attribute__((address_space(1))) unsigned int*)g,
      (__attribute__((address_space(3))) unsigned int*)l, 16, 0, 0);
}

__device__ __forceinline__ float aload(const float* p) {   // L2-coherent load
    return __hip_atomic_load(p, __ATOMIC_RELAXED, __HIP_MEMORY_SCOPE_AGENT);
}

__device__ __forceinline__ float squash16(float s) {       // over o-group of 16
    float ns = s * s;
    #pragma unroll
    for (int d = 1; d < 16; d <<= 1) ns += __shfl_xor(ns, d);
    return s * (sqrtf(ns) / (1.0f + ns));
}

// guarded grid barrier: all NBLK blocks co-resident by construction.
__device__ __forceinline__ void gridbar(unsigned* cnt, unsigned* gen, unsigned nblk) {
    __syncthreads();
    if (threadIdx.x == 0) {
        __threadfence();
        unsigned g = __hip_atomic_load(gen, __ATOMIC_RELAXED, __HIP_MEMORY_SCOPE_AGENT);
        unsigned a = __hip_atomic_fetch_add(cnt, 1u, __ATOMIC_ACQ_REL, __HIP_MEMORY_SCOPE_AGENT);
        if (a == nblk - 1) {
            __hip_atomic_store(cnt, 0u, __ATOMIC_RELAXED, __HIP_MEMORY_SCOPE_AGENT);
            __hip_atomic_store(gen, g + 1u, __ATOMIC_RELEASE, __HIP_MEMORY_SCOPE_AGENT);
        } else {
            long guard = 0;
            while (__hip_atomic_load(gen, __ATOMIC_ACQUIRE, __HIP_MEMORY_SCOPE_AGENT) == g)
                if (++guard > 100000000L) break;           // fail visibly, never hang
        }
    }
    __syncthreads();
}

// ---------------------------------------------------------------------------
// one W-streaming phase: 16 steps x 4 routes (2 pairs), wave-private 2x4KB
// double buffer, DMA-staged (source chunk pi), conflict-free ds_read (s0/s1).
//   u = mfma_f32_32x32x16_f16(Ah,Bh): lane->b=lane&31; reg j->row
//   (j&3)+8*(j>>2)+4*kh; row<16 route-even o=row, row>=16 route-odd o=row-16.
//   MODE 1: Lv per parity = 8 fma + shfl_xor(32); e=exp; accE/accZ.
//   MODE 0: accumulate u straight into the MFMA C operand.
// Epilogue: LDS tree (red overlays Wl) + device atomics to E (and Z).
// ---------------------------------------------------------------------------
template <int MODE, int DIR>
__device__ __forceinline__ void phase(
        const float4* __restrict__ W4, float4 (&Wl)[2][256], float* red,
        int rbase, int c, int tid, int wv, int lane, int b, int kh,
        int pi, int s0, int s1, half8_t Bh, const float (&vv)[8],
        float* __restrict__ E, float* __restrict__ Z)
{
    f32x16_t a1 = {0.f,0.f,0.f,0.f,0.f,0.f,0.f,0.f,
                   0.f,0.f,0.f,0.f,0.f,0.f,0.f,0.f};
    const f32x16_t z16 = a1;
    float accE[16];
    #pragma unroll
    for (int j = 0; j < 16; ++j) accE[j] = 0.f;
    float accZ0 = 0.f, accZ1 = 0.f;

    #define SIDX(i) (DIR ? (15 - (i)) : (i))
    #define STAGE(si, bf)                                                     \
    {                                                                         \
        _Pragma("unroll")                                                     \
        for (int q = 0; q < 2; ++q) {                                         \
            size_t re = (size_t)(rbase + wv * 64 + (si) * 4 + q * 2);         \
            gload_lds16(W4 + (re * 16 + c) * 64 + pi, &Wl[bf][q * 128]);      \
            gload_lds16(W4 + ((re + 1) * 16 + c) * 64 + pi,                   \
                        &Wl[bf][q * 128 + 64]);                               \
        }                                                                     \
    }

    STAGE(SIDX(0), 0);

    #pragma unroll 1
    for (int i = 0; i < 16; ++i) {
        if (i < 15) {
            STAGE(SIDX(i + 1), (i + 1) & 1);
            asm volatile("s_waitcnt vmcnt(4)" ::: "memory");  // step i landed
        } else {
            asm volatile("s_waitcnt vmcnt(0)" ::: "memory");
        }
        const float4* Wb = &Wl[i & 1][0];

        #pragma unroll
        for (int q = 0; q < 2; ++q) {
            float4 wa = Wb[q * 128 + s0];
            float4 wb = Wb[q * 128 + s1];
            float wf[8] = {wa.x, wa.y, wa.z, wa.w, wb.x, wb.y, wb.z, wb.w};
            half8_t Ah;
            #pragma unroll
            for (int j = 0; j < 8; ++j) Ah[j] = (_Float16)wf[j];
            if (MODE) {
                f32x16_t t = __builtin_amdgcn_mfma_f32_32x32x16_f16(Ah, Bh, z16, 0, 0, 0);
                float pe = 0.f, po = 0.f;
                #pragma unroll
                for (int rb = 0; rb < 4; ++rb) {
                    pe += t[rb] * vv[rb] + t[4 + rb] * vv[4 + rb];
                    po += t[8 + rb] * vv[rb] + t[12 + rb] * vv[4 + rb];
                }
                pe += __shfl_xor(pe, 32);
                po += __shfl_xor(po, 32);
                float e0 = __expf(pe), e1 = __expf(po);
                accZ0 += e0;  accZ1 += e1;
                #pragma unroll
                for (int j = 0; j < 8; ++j)  accE[j] += e0 * t[j];
                #pragma unroll
                for (int j = 8; j < 16; ++j) accE[j] += e1 * t[j];
            } else {
                a1 = __builtin_amdgcn_mfma_f32_32x32x16_f16(Ah, Bh, a1, 0, 0, 0);
            }
        }
    }
    #undef STAGE
    #undef SIDX
    if (!MODE) {
        #pragma unroll
        for (int j = 0; j < 16; ++j) accE[j] = a1[j];
    }

    __syncthreads();                               // all waves done with Wl
    float4 e0 = make_float4(accE[0] + accE[8],  accE[1] + accE[9],
                            accE[2] + accE[10], accE[3] + accE[11]);
    float4 e1 = make_float4(accE[4] + accE[12], accE[5] + accE[13],
                            accE[6] + accE[14], accE[7] + accE[15]);
    *(float4*)&red[wv * 512 + b * 16 + 4 * kh]     = e0;
    *(float4*)&red[wv * 512 + b * 16 + 8 + 4 * kh] = e1;
    if (MODE && kh == 0) red[4096 + wv * 32 + b] = accZ0 + accZ1;
    __syncthreads();
    {
        float s = 0.f;
        #pragma unroll
        for (int w2 = 0; w2 < 8; ++w2) s += red[w2 * 512 + tid];
        atomicAdd(&E[(tid >> 4) * 256 + c * 16 + (tid & 15)], s);
    }
    if (MODE && tid < 32) {
        float sz = 0.f;
        #pragma unroll
        for (int w2 = 0; w2 < 8; ++w2) sz += red[4096 + w2 * 32 + tid];
        atomicAdd(&Z[tid * 16 + c], sz);
    }
}

// ---------------------------------------------------------------------------
// k_caps: whole routing computation. Grid 512: c = g&15, bq = g>>4 owns
// routes [bq*512, +512); wave owns 64 routes. Phases separated by gridbar.
// ---------------------------------------------------------------------------
__global__ __launch_bounds__(512, 2)
void k_caps(const float* __restrict__ W, const float* __restrict__ x,
            float* __restrict__ E1, float* __restrict__ E2, float* __restrict__ Z2,
            float* __restrict__ E3, float* __restrict__ Z3,
            unsigned* __restrict__ bar, float* __restrict__ out)
{
    __shared__ float4 WlS[8][2][256];              // 64 KB (red overlays)
    __shared__ float vt[512];                      // current v table (b*16+o)
    __shared__ float v1s[512];                     // saved v1
    float* red = (float*)WlS;

    const int g = blockIdx.x;
    const int c = g & 15;
    const int rbase = (g >> 4) * 512;
    const int tid = threadIdx.x;
    const int wv = tid >> 6;
    const int lane = tid & 63;
    const int b = lane & 31;
    const int kh = lane >> 5;
    const int rsel = (lane >> 4) & 1;

    const float4* W4 = (const float4*)W;
    const int pi = lane ^ ((lane >> 3) & 7);
    const int c0 = rsel * 64 + (lane & 15) * 4 + kh * 2;
    const int s0 = c0 ^ ((c0 >> 3) & 7);
    const int s1 = s0 ^ 1;
    const int slot = (tid >> 4) * 256 + c * 16 + (tid & 15);   // E index
    const int zslot = (tid >> 4) * 16 + c;                     // Z index

    half8_t Bh;
    {
        const float4* xb = (const float4*)(x + (b * 16 + c) * 16) + kh * 2;
        float4 x0 = xb[0], x1 = xb[1];
        float xv[8] = {x0.x, x0.y, x0.z, x0.w, x1.x, x1.y, x1.z, x1.w};
        #pragma unroll
        for (int j = 0; j < 8; ++j) Bh[j] = (_Float16)xv[j];
    }
    float vv[8];
    #pragma unroll
    for (int j = 0; j < 8; ++j) vv[j] = 0.f;

    // ---- phase 0: S = sum_r u -> E1 ----
    phase<0, 0>(W4, WlS[wv], red, rbase, c, tid, wv, lane, b, kh,
                pi, s0, s1, Bh, vv, E1, Z2);
    gridbar(bar, bar + 1, 512);

    // v1 = squash(E1/R); keep copy
    {
        float s = aload(&E1[slot]) * (1.0f / 16384.0f);
        float vq = squash16(s);
        vt[tid] = vq;  v1s[tid] = vq;
    }
    __syncthreads();
    #pragma unroll
    for (int rb = 0; rb < 4; ++rb) {
        vv[rb]     = vt[b * 16 + 4 * kh + rb];
        vv[4 + rb] = vt[b * 16 + 8 + 4 * kh + rb];
    }

    // ---- phase 1: logits <u,v1> -> E2,Z2 (reverse walk: L2/L3-warm tail) ----
    phase<1, 1>(W4, WlS[wv], red, rbase, c, tid, wv, lane, b, kh,
                pi, s0, s1, Bh, vv, E2, Z2);
    gridbar(bar, bar + 1, 512);

    // vsum = v1 + squash(E2/Z2)
    {
        float s = aload(&E2[slot]) / aload(&Z2[zslot]);
        vt[tid] = v1s[tid] + squash16(s);
    }
    __syncthreads();
    #pragma unroll
    for (int rb = 0; rb < 4; ++rb) {
        vv[rb]     = vt[b * 16 + 4 * kh + rb];
        vv[4 + rb] = vt[b * 16 + 8 + 4 * kh + rb];
    }

    // ---- phase 2: logits <u,v1+v2> -> E3,Z3 (forward) ----
    phase<1, 0>(W4, WlS[wv], red, rbase, c, tid, wv, lane, b, kh,
                pi, s0, s1, Bh, vv, E3, Z3);
    gridbar(bar, bar + 1, 512);

    // out = squash(E3/Z3), written by the 16 bq==0 blocks
    if (rbase == 0) {
        float s = aload(&E3[slot]) / aload(&Z3[zslot]);
        out[slot] = squash16(s);
    }
}

// ---------------------------------------------------------------------------
// launch
// ---------------------------------------------------------------------------
extern "C" void kernel_launch(void* const* d_in, const int* in_sizes, int n_in,
                              void* d_out, int out_size, void* d_ws, size_t ws_size,
                              hipStream_t stream) {
    const float* x = (const float*)d_in[0];        // 8192 floats
    const float* W = (const float*)d_in[1];        // 67108864 floats (256 MB)
    float* out = (float*)d_out;                    // 8192 floats
    float* ws = (float*)d_ws;

    float* E1 = ws + 0;            // 8192
    float* E2 = ws + 8192;         // 8192
    float* Z2 = ws + 16384;        // 512
    float* E3 = ws + 16896;        // 8192
    float* Z3 = ws + 25088;        // 512
    unsigned* bar = (unsigned*)(ws + 25600);       // cnt, gen

    hipMemsetAsync(ws, 0, 25664 * sizeof(float), stream);

    k_caps<<<512, 512, 0, stream>>>(W, x, E1, E2, Z2, E3, Z3, bar, out);
}

// Round 17
// 480.224 us; speedup vs baseline: 1.5156x; 1.5156x over previous
//
#include <hip/hip_runtime.h>
#include <math.h>

// B=32, R=16384, C=16, IC=16, OC=16, 3 routing iterations.
// x: (B,C,IC) fp32; W: (R,C,OC,IC) fp32 (256 MB); out: (B,C,OC) fp32.
//
// R17 theory (from R16's finally-visible counters): all W passes are served
// mostly by Infinity Cache at ~1.6 TB/s regardless of kernel structure
// (VALUBusy 6%, MfmaUtil 1%, HBM 0.8 TB/s, no spills, no conflicts -- yet
// 768 MB consumed in 479 us). The remaining lever is BYTES, not structure:
// convert W to fp16 ONCE (dense stream at HBM rate) into a fragment-ready
// c-major layout; all 3 routing passes then read 128 MB (L3-resident) and
// each lane's A-fragment is a single contiguous dwordx4 -- no LDS staging,
// no per-pass conversion. fp16 precision proven R15/R16 (3.9e-3 < 1.5e-2).
// R16 lessons: fusion/barriers regress (466->727); separate dispatches are
// ~free (R15: 3x155+eps = 466). No cooperative launch under graph capture.
//
// W16 layout (halves): fragment lane l of (c, pair p) at
//   ((c*8192 + p)*64 + l)*8,  l = rsel*16 + o + 32*kh,
//   element j = W[2p+rsel][c][o][8*kh+j]  -- exactly the mfma_32x32x16 A-frag
//   (lane->m=l&31=rsel*16+o, k=8*kh+j). 1 KB per (c,pair), c-major: each
//   routing block streams a contiguous 128 KB region.

typedef _Float16 half8_t __attribute__((ext_vector_type(8)));
typedef float f32x16_t __attribute__((ext_vector_type(16)));

// ---------------------------------------------------------------------------
// k_conv: W fp32 -> W16 fp16 fragment layout. One thread = 8 elements (32 B
// read, 16 B write). t = ((r*16+c)*16+o)*2+kh -> reads are perfectly dense;
// writes cover each 1 KB fragment block in four 256 B runs (full lines).
// ---------------------------------------------------------------------------
__global__ __launch_bounds__(256) void k_conv(const float4* __restrict__ W4,
                                              _Float16* __restrict__ W16) {
    int t = blockIdx.x * 256 + threadIdx.x;        // [0, 8388608)
    int kh = t & 1, o = (t >> 1) & 15, c = (t >> 5) & 15, r = t >> 9;
    float4 a = W4[(size_t)t * 2], b = W4[(size_t)t * 2 + 1];
    half8_t h;
    h[0] = (_Float16)a.x; h[1] = (_Float16)a.y; h[2] = (_Float16)a.z; h[3] = (_Float16)a.w;
    h[4] = (_Float16)b.x; h[5] = (_Float16)b.y; h[6] = (_Float16)b.z; h[7] = (_Float16)b.w;
    size_t dst = ((size_t)(c * 8192 + (r >> 1)) * 64
                  + ((r & 1) * 16 + o + 32 * kh)) * 8;
    *(uint4*)(W16 + dst) = *(uint4*)&h;
}

// ---------------------------------------------------------------------------
// k_v1 / k_vsum / k_vout: tiny squash kernels (unchanged).
// ---------------------------------------------------------------------------
__global__ __launch_bounds__(256) void k_v1(const float* __restrict__ E1,
                                            float* __restrict__ v1) {
    int t = blockIdx.x * 256 + threadIdx.x;
    float s = E1[t] * (1.0f / 16384.0f);
    float ns = s * s;
    #pragma unroll
    for (int d = 1; d < 16; d <<= 1) ns += __shfl_xor(ns, d);
    v1[t] = s * (sqrtf(ns) / (1.0f + ns));
}

__global__ __launch_bounds__(256) void k_vsum(const float* __restrict__ E,
                                              const float* __restrict__ Z,
                                              const float* __restrict__ v1,
                                              float* __restrict__ vsum) {
    int t = blockIdx.x * 256 + threadIdx.x;
    float s = E[t] / Z[t >> 4];
    float ns = s * s;
    #pragma unroll
    for (int d = 1; d < 16; d <<= 1) ns += __shfl_xor(ns, d);
    vsum[t] = v1[t] + s * (sqrtf(ns) / (1.0f + ns));
}

__global__ __launch_bounds__(256) void k_vout(const float* __restrict__ E,
                                              const float* __restrict__ Z,
                                              float* __restrict__ dst) {
    int t = blockIdx.x * 256 + threadIdx.x;
    float s = E[t] / Z[t >> 4];
    float ns = s * s;
    #pragma unroll
    for (int d = 1; d < 16; d <<= 1) ns += __shfl_xor(ns, d);
    dst[t] = s * (sqrtf(ns) / (1.0f + ns));
}

// ---------------------------------------------------------------------------
// k_route<MODE,REV>: one W16-streaming pass. Block 512 = 8 waves; grid
// (16 c, 64 bx). Wave wv owns pairs [bx*128 + wv*16, +16): reads a contiguous
// 16 KB stream; block reads a contiguous 128 KB region of W16[c].
// Per pair: one prefetched uint4 (= the lane's whole A-fragment, 8 halves),
// one mfma_f32_32x32x16_f16, then
//   MODE 1: Lv per route-parity = 8 fma + shfl_xor(32); e=exp; accE/accZ.
//   MODE 0: accumulate u straight into the MFMA C operand (E1 = sum_r u).
// D-layout (HW-verified): lane->b=lane&31; reg j->row=(j&3)+8*(j>>2)+4*kh;
// row<16 route-even o=row, row>=16 route-odd o=row-16.
// Prefetch depth 4 via f[4] + unroll 4 (indices compile-time; live ~60 regs).
// Epilogue: 17 KB LDS tree + atomics (R15-proven). REV reverses bx walk.
// ---------------------------------------------------------------------------
template <int MODE, int REV>
__global__ __launch_bounds__(512, 2)
void k_route(const _Float16* __restrict__ W16,
             const float* __restrict__ x,
             const float* __restrict__ v,
             float* __restrict__ E,
             float* __restrict__ Z) {
    __shared__ float red[8 * 512 + 256];           // 17 KB epilogue scratch
    const int c = blockIdx.x;
    const int bxr = (int)blockIdx.y;
    const int bx = REV ? (63 - bxr) : bxr;
    const int tid = threadIdx.x;
    const int wv = tid >> 6;                       // [0,8)
    const int lane = tid & 63;
    const int b = lane & 31;                       // batch (N-col / D-col)
    const int kh = lane >> 5;                      // k-half

    // ---- B fragment from x (single f16) ----
    half8_t Bh;
    {
        const float4* xb = (const float4*)(x + (b * 16 + c) * 16) + kh * 2;
        float4 x0 = xb[0], x1 = xb[1];
        float xv[8] = {x0.x, x0.y, x0.z, x0.w, x1.x, x1.y, x1.z, x1.w};
        #pragma unroll
        for (int j = 0; j < 8; ++j) Bh[j] = (_Float16)xv[j];
    }
    // v slice for this lane: o in {4kh..4kh+3} u {8+4kh..11+4kh}
    float vv[8];
    if (MODE) {
        const float4* vb = (const float4*)(v + (b * 16 + c) * 16);
        float4 v0 = vb[kh], v1 = vb[2 + kh];
        vv[0]=v0.x; vv[1]=v0.y; vv[2]=v0.z; vv[3]=v0.w;
        vv[4]=v1.x; vv[5]=v1.y; vv[6]=v1.z; vv[7]=v1.w;
    }

    f32x16_t a1 = {0.f,0.f,0.f,0.f,0.f,0.f,0.f,0.f,
                   0.f,0.f,0.f,0.f,0.f,0.f,0.f,0.f};
    const f32x16_t z16 = a1;
    float accE[16];
    #pragma unroll
    for (int j = 0; j < 16; ++j) accE[j] = 0.f;
    float accZ0 = 0.f, accZ1 = 0.f;

    // per-lane fragment stream: pair p -> base[p*64]
    const uint4* base = (const uint4*)W16
        + ((size_t)(c * 8192 + bx * 128 + wv * 16)) * 64 + lane;

    uint4 f[4];
    #pragma unroll
    for (int j = 0; j < 4; ++j) f[j] = base[j * 64];

    #pragma unroll 4
    for (int p = 0; p < 16; ++p) {
        uint4 cur = f[p & 3];
        if (p + 4 < 16) f[p & 3] = base[(size_t)(p + 4) * 64];
        half8_t Ah;
        *(uint4*)&Ah = cur;
        if (MODE) {
            f32x16_t t = __builtin_amdgcn_mfma_f32_32x32x16_f16(Ah, Bh, z16, 0, 0, 0);
            float pe = 0.f, po = 0.f;
            #pragma unroll
            for (int rb = 0; rb < 4; ++rb) {
                pe += t[rb] * vv[rb] + t[4 + rb] * vv[4 + rb];
                po += t[8 + rb] * vv[rb] + t[12 + rb] * vv[4 + rb];
            }
            pe += __shfl_xor(pe, 32);              // join k-halves (o-halves)
            po += __shfl_xor(po, 32);
            float e0 = __expf(pe), e1 = __expf(po);
            accZ0 += e0;  accZ1 += e1;
            #pragma unroll
            for (int j = 0; j < 8; ++j)  accE[j] += e0 * t[j];
            #pragma unroll
            for (int j = 8; j < 16; ++j) accE[j] += e1 * t[j];
        } else {
            a1 = __builtin_amdgcn_mfma_f32_32x32x16_f16(Ah, Bh, a1, 0, 0, 0);
        }
    }
    if (!MODE) {
        #pragma unroll
        for (int j = 0; j < 16; ++j) accE[j] = a1[j];
    }

    // ---- epilogue: LDS tree + atomics ----
    float4 e0 = make_float4(accE[0] + accE[8],  accE[1] + accE[9],
                            accE[2] + accE[10], accE[3] + accE[11]);
    float4 e1 = make_float4(accE[4] + accE[12], accE[5] + accE[13],
                            accE[6] + accE[14], accE[7] + accE[15]);
    *(float4*)&red[wv * 512 + b * 16 + 4 * kh]     = e0;
    *(float4*)&red[wv * 512 + b * 16 + 8 + 4 * kh] = e1;
    if (MODE && kh == 0) red[4096 + wv * 32 + b] = accZ0 + accZ1;
    __syncthreads();
    {
        float s = 0.f;
        #pragma unroll
        for (int w2 = 0; w2 < 8; ++w2) s += red[w2 * 512 + tid];
        atomicAdd(&E[(tid >> 4) * 256 + c * 16 + (tid & 15)], s);
    }
    if (MODE && tid < 32) {
        float sz = 0.f;
        #pragma unroll
        for (int w2 = 0; w2 < 8; ++w2) sz += red[4096 + w2 * 32 + tid];
        atomicAdd(&Z[tid * 16 + c], sz);
    }
}

// ---------------------------------------------------------------------------
// launch
// ---------------------------------------------------------------------------
extern "C" void kernel_launch(void* const* d_in, const int* in_sizes, int n_in,
                              void* d_out, int out_size, void* d_ws, size_t ws_size,
                              hipStream_t stream) {
    const float* x = (const float*)d_in[0];        // 8192 floats
    const float* W = (const float*)d_in[1];        // 67108864 floats (256 MB)
    float* out = (float*)d_out;                    // 8192 floats
    float* ws = (float*)d_ws;

    float* E1   = ws + 0;          // 8192  (S = sum_r u)
    float* E2   = ws + 8192;       // 8192
    float* Z2   = ws + 16384;      // 512
    float* E3   = ws + 16896;      // 8192
    float* Z3   = ws + 25088;      // 512   (zeroed region ends at 25600)
    float* v1   = ws + 25600;      // 8192
    float* vsum = ws + 33792;      // 8192
    _Float16* W16 = (_Float16*)(ws + 65536);       // 64M halves = 128 MB

    hipMemsetAsync(ws, 0, 25600 * sizeof(float), stream);

    // one-time dense fp32->fp16 repack (256 MB read + 128 MB write, HBM rate)
    k_conv<<<32768, 256, 0, stream>>>((const float4*)W, W16);

    // iter 1: S = sum_r u (uniform routing), W16 pass 1 (forward)
    k_route<0, 0><<<dim3(16, 64), 512, 0, stream>>>(W16, x, v1, E1, Z2);
    k_v1<<<32, 256, 0, stream>>>(E1, v1);          // v1 = squash(S/R)

    // iter 2: logits = <u, v1>, W16 pass 2 (reverse: L3-warm tail)
    k_route<1, 1><<<dim3(16, 64), 512, 0, stream>>>(W16, x, v1, E2, Z2);
    k_vsum<<<32, 256, 0, stream>>>(E2, Z2, v1, vsum);  // vsum = v1 + squash(E2/Z2)

    // iter 3: logits = <u, v1+v2>, W16 pass 3 (forward)
    k_route<1, 0><<<dim3(16, 64), 512, 0, stream>>>(W16, x, vsum, E3, Z3);
    k_vout<<<32, 256, 0, stream>>>(E3, Z3, out);
}

// Round 18
// 470.791 us; speedup vs baseline: 1.5460x; 1.0200x over previous
//
#include <hip/hip_runtime.h>
#include <math.h>

// B=32, R=16384, C=16, IC=16, OC=16, 3 routing iterations.
// x: (B,C,IC) fp32; W: (R,C,OC,IC) fp32 (256 MB); out: (B,C,OC) fp32.
//
// R18 theory: routes are LATENCY-bound, not byte-bound. Evidence: R17 halved
// bytes (256->128 MB/pass, dense fragment layout) -> neutral; R16 counters
// show nothing busy (VALU 6%, MFMA 1%, HBM 10%, no spills). R17's route held
// only f[4] = 64 B in flight per wave; at 16 waves/CU and ~350ns latency,
// Little's law -> ~1.5 TB/s chip-wide = the invariant ceiling of R4..R17.
// Fix (single variable): issue the wave's ENTIRE pass workload (16 loads,
// 16 KB) up front -> 256 KB/CU in flight -> latency fully covered.
// Carried: W16 fragment repack (R17), single-term fp16 MFMA (R15, absmax
// 3.9e-3 vs threshold 1.5e-2), LDS-tree+atomic epilogue, no cooperative
// launch (R12), no fusion/barriers (R16: 466->727).

typedef _Float16 half8_t __attribute__((ext_vector_type(8)));
typedef float f32x16_t __attribute__((ext_vector_type(16)));

// ---------------------------------------------------------------------------
// k_conv: W fp32 -> W16 fp16 fragment layout. One thread = 8 elements (32 B
// dense read, 16 B write). High occupancy + 2 indep loads/thread -> BW-bound.
// ---------------------------------------------------------------------------
__global__ __launch_bounds__(256) void k_conv(const float4* __restrict__ W4,
                                              _Float16* __restrict__ W16) {
    int t = blockIdx.x * 256 + threadIdx.x;        // [0, 8388608)
    int kh = t & 1, o = (t >> 1) & 15, c = (t >> 5) & 15, r = t >> 9;
    float4 a = W4[(size_t)t * 2], b = W4[(size_t)t * 2 + 1];
    half8_t h;
    h[0] = (_Float16)a.x; h[1] = (_Float16)a.y; h[2] = (_Float16)a.z; h[3] = (_Float16)a.w;
    h[4] = (_Float16)b.x; h[5] = (_Float16)b.y; h[6] = (_Float16)b.z; h[7] = (_Float16)b.w;
    size_t dst = ((size_t)(c * 8192 + (r >> 1)) * 64
                  + ((r & 1) * 16 + o + 32 * kh)) * 8;
    *(uint4*)(W16 + dst) = *(uint4*)&h;
}

// ---------------------------------------------------------------------------
// tiny squash kernels (unchanged)
// ---------------------------------------------------------------------------
__global__ __launch_bounds__(256) void k_v1(const float* __restrict__ E1,
                                            float* __restrict__ v1) {
    int t = blockIdx.x * 256 + threadIdx.x;
    float s = E1[t] * (1.0f / 16384.0f);
    float ns = s * s;
    #pragma unroll
    for (int d = 1; d < 16; d <<= 1) ns += __shfl_xor(ns, d);
    v1[t] = s * (sqrtf(ns) / (1.0f + ns));
}

__global__ __launch_bounds__(256) void k_vsum(const float* __restrict__ E,
                                              const float* __restrict__ Z,
                                              const float* __restrict__ v1,
                                              float* __restrict__ vsum) {
    int t = blockIdx.x * 256 + threadIdx.x;
    float s = E[t] / Z[t >> 4];
    float ns = s * s;
    #pragma unroll
    for (int d = 1; d < 16; d <<= 1) ns += __shfl_xor(ns, d);
    vsum[t] = v1[t] + s * (sqrtf(ns) / (1.0f + ns));
}

__global__ __launch_bounds__(256) void k_vout(const float* __restrict__ E,
                                              const float* __restrict__ Z,
                                              float* __restrict__ dst) {
    int t = blockIdx.x * 256 + threadIdx.x;
    float s = E[t] / Z[t >> 4];
    float ns = s * s;
    #pragma unroll
    for (int d = 1; d < 16; d <<= 1) ns += __shfl_xor(ns, d);
    dst[t] = s * (sqrtf(ns) / (1.0f + ns));
}

// ---------------------------------------------------------------------------
// k_route<MODE,REV>: one W16-streaming pass. Block 512 = 8 waves; grid
// (16 c, 64 bx). Wave wv owns pairs [bx*128 + wv*16, +16) = contiguous 16 KB.
// ALL 16 fragment loads issued up front (f[0..15], 64 VGPR) -> 16 KB/wave in
// flight; compute then consumes them in order (compiler inserts per-use
// vmcnt). Per pair: one mfma_f32_32x32x16_f16; MODE 1 adds the softmax chain,
// MODE 0 accumulates u into the MFMA C operand.
// D-layout (HW-verified): lane->b=lane&31; reg j->row=(j&3)+8*(j>>2)+4*kh;
// row<16 route-even o=row, row>=16 route-odd o=row-16.
// Live regs ~105 (f 64 + accE 16 + vv 8 + misc) < 128 cap of (512,2).
// ---------------------------------------------------------------------------
template <int MODE, int REV>
__global__ __launch_bounds__(512, 2)
void k_route(const _Float16* __restrict__ W16,
             const float* __restrict__ x,
             const float* __restrict__ v,
             float* __restrict__ E,
             float* __restrict__ Z) {
    __shared__ float red[8 * 512 + 256];           // 17 KB epilogue scratch
    const int c = blockIdx.x;
    const int bxr = (int)blockIdx.y;
    const int bx = REV ? (63 - bxr) : bxr;
    const int tid = threadIdx.x;
    const int wv = tid >> 6;                       // [0,8)
    const int lane = tid & 63;
    const int b = lane & 31;                       // batch (N-col / D-col)
    const int kh = lane >> 5;                      // k-half

    // ---- B fragment from x (single f16) ----
    half8_t Bh;
    {
        const float4* xb = (const float4*)(x + (b * 16 + c) * 16) + kh * 2;
        float4 x0 = xb[0], x1 = xb[1];
        float xv[8] = {x0.x, x0.y, x0.z, x0.w, x1.x, x1.y, x1.z, x1.w};
        #pragma unroll
        for (int j = 0; j < 8; ++j) Bh[j] = (_Float16)xv[j];
    }
    // v slice for this lane: o in {4kh..4kh+3} u {8+4kh..11+4kh}
    float vv[8];
    if (MODE) {
        const float4* vb = (const float4*)(v + (b * 16 + c) * 16);
        float4 v0 = vb[kh], v1 = vb[2 + kh];
        vv[0]=v0.x; vv[1]=v0.y; vv[2]=v0.z; vv[3]=v0.w;
        vv[4]=v1.x; vv[5]=v1.y; vv[6]=v1.z; vv[7]=v1.w;
    }

    f32x16_t a1 = {0.f,0.f,0.f,0.f,0.f,0.f,0.f,0.f,
                   0.f,0.f,0.f,0.f,0.f,0.f,0.f,0.f};
    const f32x16_t z16 = a1;
    float accE[16];
    #pragma unroll
    for (int j = 0; j < 16; ++j) accE[j] = 0.f;
    float accZ0 = 0.f, accZ1 = 0.f;

    // per-lane fragment stream: pair p -> base[p*64]
    const uint4* base = (const uint4*)W16
        + ((size_t)(c * 8192 + bx * 128 + wv * 16)) * 64 + lane;

    // issue the ENTIRE pass's loads up front: 16 KB/wave in flight
    uint4 f[16];
    #pragma unroll
    for (int p = 0; p < 16; ++p) f[p] = base[(size_t)p * 64];

    #pragma unroll
    for (int p = 0; p < 16; ++p) {
        half8_t Ah;
        *(uint4*)&Ah = f[p];
        if (MODE) {
            f32x16_t t = __builtin_amdgcn_mfma_f32_32x32x16_f16(Ah, Bh, z16, 0, 0, 0);
            float pe = 0.f, po = 0.f;
            #pragma unroll
            for (int rb = 0; rb < 4; ++rb) {
                pe += t[rb] * vv[rb] + t[4 + rb] * vv[4 + rb];
                po += t[8 + rb] * vv[rb] + t[12 + rb] * vv[4 + rb];
            }
            pe += __shfl_xor(pe, 32);              // join k-halves (o-halves)
            po += __shfl_xor(po, 32);
            float e0 = __expf(pe), e1 = __expf(po);
            accZ0 += e0;  accZ1 += e1;
            #pragma unroll
            for (int j = 0; j < 8; ++j)  accE[j] += e0 * t[j];
            #pragma unroll
            for (int j = 8; j < 16; ++j) accE[j] += e1 * t[j];
        } else {
            a1 = __builtin_amdgcn_mfma_f32_32x32x16_f16(Ah, Bh, a1, 0, 0, 0);
        }
    }
    if (!MODE) {
        #pragma unroll
        for (int j = 0; j < 16; ++j) accE[j] = a1[j];
    }

    // ---- epilogue: LDS tree + atomics ----
    float4 e0 = make_float4(accE[0] + accE[8],  accE[1] + accE[9],
                            accE[2] + accE[10], accE[3] + accE[11]);
    float4 e1 = make_float4(accE[4] + accE[12], accE[5] + accE[13],
                            accE[6] + accE[14], accE[7] + accE[15]);
    *(float4*)&red[wv * 512 + b * 16 + 4 * kh]     = e0;
    *(float4*)&red[wv * 512 + b * 16 + 8 + 4 * kh] = e1;
    if (MODE && kh == 0) red[4096 + wv * 32 + b] = accZ0 + accZ1;
    __syncthreads();
    {
        float s = 0.f;
        #pragma unroll
        for (int w2 = 0; w2 < 8; ++w2) s += red[w2 * 512 + tid];
        atomicAdd(&E[(tid >> 4) * 256 + c * 16 + (tid & 15)], s);
    }
    if (MODE && tid < 32) {
        float sz = 0.f;
        #pragma unroll
        for (int w2 = 0; w2 < 8; ++w2) sz += red[4096 + w2 * 32 + tid];
        atomicAdd(&Z[tid * 16 + c], sz);
    }
}

// ---------------------------------------------------------------------------
// launch
// ---------------------------------------------------------------------------
extern "C" void kernel_launch(void* const* d_in, const int* in_sizes, int n_in,
                              void* d_out, int out_size, void* d_ws, size_t ws_size,
                              hipStream_t stream) {
    const float* x = (const float*)d_in[0];        // 8192 floats
    const float* W = (const float*)d_in[1];        // 67108864 floats (256 MB)
    float* out = (float*)d_out;                    // 8192 floats
    float* ws = (float*)d_ws;

    float* E1   = ws + 0;          // 8192  (S = sum_r u)
    float* E2   = ws + 8192;       // 8192
    float* Z2   = ws + 16384;      // 512
    float* E3   = ws + 16896;      // 8192
    float* Z3   = ws + 25088;      // 512   (zeroed region ends at 25600)
    float* v1   = ws + 25600;      // 8192
    float* vsum = ws + 33792;      // 8192
    _Float16* W16 = (_Float16*)(ws + 65536);       // 64M halves = 128 MB

    hipMemsetAsync(ws, 0, 25600 * sizeof(float), stream);

    // one-time dense fp32->fp16 repack
    k_conv<<<32768, 256, 0, stream>>>((const float4*)W, W16);

    // iter 1: S = sum_r u (uniform routing), W16 pass 1 (forward)
    k_route<0, 0><<<dim3(16, 64), 512, 0, stream>>>(W16, x, v1, E1, Z2);
    k_v1<<<32, 256, 0, stream>>>(E1, v1);          // v1 = squash(S/R)

    // iter 2: logits = <u, v1>, W16 pass 2 (reverse: L3-warm tail)
    k_route<1, 1><<<dim3(16, 64), 512, 0, stream>>>(W16, x, v1, E2, Z2);
    k_vsum<<<32, 256, 0, stream>>>(E2, Z2, v1, vsum);  // vsum = v1 + squash(E2/Z2)

    // iter 3: logits = <u, v1+v2>, W16 pass 3 (forward)
    k_route<1, 0><<<dim3(16, 64), 512, 0, stream>>>(W16, x, vsum, E3, Z3);
    k_vout<<<32, 256, 0, stream>>>(E3, Z3, out);
}